// Round 9
// baseline (50.904 us; speedup 1.0000x reference)
//
#include <hip/hip_runtime.h>
#include <math.h>

#define BB 4
#define NN 16384
#define CC 128
#define MM 128
#define SS 512
#define OUT_ROW 131                    // 3 coords + 128 features
#define NSEG 256                       // 16384 / 64 segments per box
#define ELEMS_PER_BOX (SS * OUT_ROW)   // 67072
#define G2 16                          // row-groups per box (32 rows each)
#define RPG2 32
#define TILE2_F4 (RPG2 * OUT_ROW / 4)  // 1048 float4s per tile
#define WROWS 8                        // rows per wave
#define WF4 (WROWS * OUT_ROW / 4)      // 262 f32x4 per wave slice

typedef float f32x4 __attribute__((ext_vector_type(4)));

// ---------------- K1: per-box stable in-box index selection ----------------
// 512 blocks (one per box) x 512 threads (8 waves).
// Emits ws_idx[bm][0..SS) with the row%cnt wrap ALREADY applied.
__global__ __launch_bounds__(512) void k1_select(
    const float* __restrict__ points,   // (B, N, 3)
    const float* __restrict__ boxes,    // (B, M, 7)
    int* __restrict__ ws_idx,           // (B*M, SS)
    int* __restrict__ ws_cnt,           // (B*M)
    float* __restrict__ out_flag)       // (B*M) as float 0/1
{
    const int bm   = blockIdx.x;
    const int b    = bm >> 7;
    const int m    = bm & (MM - 1);
    const int tid  = threadIdx.x;
    const int lane = tid & 63;
    const int wave = tid >> 6;

    __shared__ unsigned long long s_mask[NSEG];
    __shared__ int s_wsum[4];

    // box params, enlarged: cz -= 0.5, d* += 1.0
    const float* bx = boxes + (size_t)(b * MM + m) * 7;
    const float cx  = bx[0];
    const float cy  = bx[1];
    const float cz  = __fadd_rn(bx[2], -0.5f);
    const float hx  = __fmul_rn(__fadd_rn(bx[3], 1.0f), 0.5f);
    const float hy  = __fmul_rn(__fadd_rn(bx[4], 1.0f), 0.5f);
    const float hz  = __fmul_rn(__fadd_rn(bx[5], 1.0f), 0.5f);
    const float yaw = bx[6];
    const float cosa = (float)cos((double)yaw);
    const float sina = (float)sin((double)yaw);
    const float zc   = __fadd_rn(cz, hz);

    const float* pbase = points + (size_t)b * NN * 3;

    // ---- Pass A: wave w handles segments [w*32, w*32+32) ----
    #pragma unroll 4
    for (int k = 0; k < 32; ++k) {
        const int s = wave * 32 + k;
        const int i = s * 64 + lane;
        const float px = pbase[i * 3 + 0];
        const float py = pbase[i * 3 + 1];
        const float pz = pbase[i * 3 + 2];
        const float sx = __fadd_rn(px, -cx);
        const float sy = __fadd_rn(py, -cy);
        const float lx = __fadd_rn(__fmul_rn(sx, cosa), __fmul_rn(sy, sina));
        const float ly = __fadd_rn(__fmul_rn(-sx, sina), __fmul_rn(sy, cosa));
        const bool in_box = (fabsf(lx) < hx) & (fabsf(ly) < hy) &
                            (fabsf(__fadd_rn(pz, -zc)) <= hz);
        const unsigned long long mask = __ballot(in_box);
        if (lane == 0) s_mask[s] = mask;
    }
    __syncthreads();

    // ---- Pass B: prefix scan over 256 segment counts (threads 0..255) ----
    unsigned long long mymask = 0ull;
    int c = 0;
    if (tid < NSEG) {
        mymask = s_mask[tid];
        c = __popcll(mymask);
    }
    int inc = c;
    #pragma unroll
    for (int d = 1; d < 64; d <<= 1) {
        int v = __shfl_up(inc, d);
        if (lane >= d) inc += v;
    }
    if (tid < NSEG && lane == 63) s_wsum[wave] = inc;
    __syncthreads();

    int woff = 0, total = 0;
    #pragma unroll
    for (int w = 0; w < 4; ++w) {
        const int v = s_wsum[w];
        if (w < wave) woff += v;
        total += v;
    }

    int* dst = ws_idx + (size_t)bm * SS;

    // ---- Pass C: emit indices (stable ascending order), first SS only ----
    if (tid < NSEG) {
        int base = woff + inc - c;          // exclusive prefix
        if (base < SS) {
            unsigned long long mk = mymask;
            while (mk) {
                const int bit = __ffsll(mk) - 1;
                mk &= mk - 1;
                dst[base] = tid * 64 + bit;
                if (++base >= SS) break;
            }
        }
    }
    __syncthreads();

    // ---- Pass D: expand with row % cnt wrap so K2 needs no division ----
    const int cnt = total;
    if (cnt > 0) {
        for (int row = cnt + tid; row < SS; row += 512)
            dst[row] = dst[row % cnt];
    }
    if (tid == 0) {
        ws_cnt[bm] = cnt;
        out_flag[bm] = (cnt == 0) ? 1.0f : 0.0f;
    }
}

// ---------------- K2: wave-independent LDS-bounce gather ----------------
// 8192 blocks x 256 threads (4 waves), 16.75 KB LDS -> 8 blocks/CU = 100% occ.
// Each wave owns an 8-row slice of the tile: NO __syncthreads anywhere —
// wave-local vmcnt/lgkmcnt ordering (compiler-inserted) is sufficient.
// Bijective XCD swizzle keeps a box's 16 groups on one XCD's L2.
__global__ __launch_bounds__(256) void k2_gather(
    const float* __restrict__ points,
    const float* __restrict__ feats,    // (B, N, C)
    const int* __restrict__ ws_idx,
    const int* __restrict__ ws_cnt,
    float* __restrict__ out_feat)       // (B, M, S, 131)
{
    const int orig = blockIdx.x;
    const int blk  = ((orig & 7) << 10) | (orig >> 3);   // 8192 = 8 XCD x 1024
    const int bm   = blk >> 4;
    const int g    = blk & (G2 - 1);
    const int row0 = g << 5;
    const int tid  = threadIdx.x;
    const int lane = tid & 63;
    const int wave = tid >> 6;

    const int cnt = ws_cnt[bm];
    // wave's contiguous output slice: 8 rows = 4192 B
    float* owave = out_feat + (size_t)bm * ELEMS_PER_BOX
                 + (size_t)(row0 + wave * WROWS) * OUT_ROW;

    if (cnt == 0) {
        const f32x4 z = (f32x4)0.0f;
        #pragma unroll
        for (int it = 0; it < 4; ++it)
            __builtin_nontemporal_store(z, (f32x4*)owave + it * 64 + lane);
        if (lane < WF4 - 256)
            __builtin_nontemporal_store(z, (f32x4*)owave + 256 + lane);
        return;
    }

    __shared__ float s_tile[RPG2 * OUT_ROW];   // 16,768 B; wave w owns [w*1048, +1048)
    float* wtile = s_tile + wave * (WROWS * OUT_ROW);

    const int b = bm >> 7;
    const float* pb = points + (size_t)b * NN * 3;
    const float* fb = feats + (size_t)b * NN * CC;
    const int half = lane >> 5;
    const int sl   = lane & 31;
    const int* idx = ws_idx + (size_t)bm * SS + row0 + wave * WROWS;

    // lanes 0..7 hold this wave's 8 row indices; distribute via shfl
    const int idxreg = idx[lane & 7];

    // issue all 4 feature gathers before any LDS write (max loads in flight)
    f32x4 vv[4];
    int rloc[4];
    #pragma unroll
    for (int p = 0; p < 4; ++p) {
        rloc[p] = p * 2 + half;                     // local row 0..7
        const int pi = __shfl(idxreg, rloc[p]);
        vv[p] = *(const f32x4*)(fb + (size_t)pi * CC + sl * 4);
    }
    // coords: lanes 0..23 cover 8 rows x 3
    float cval = 0.0f;
    int coff = 0;
    if (lane < WROWS * 3) {
        const int r = lane / 3, c = lane - r * 3;
        cval = pb[__shfl(idxreg, r) * 3 + c];
        coff = r * OUT_ROW + c;
    }

    #pragma unroll
    for (int p = 0; p < 4; ++p) {
        float* d = wtile + rloc[p] * OUT_ROW + 3 + sl * 4;
        d[0] = vv[p].x; d[1] = vv[p].y; d[2] = vv[p].z; d[3] = vv[p].w;
    }
    if (lane < WROWS * 3) wtile[coff] = cval;

    // stream the wave's own slice out: 262 aligned NT dwordx4 (no barrier —
    // same wave wrote it; lgkmcnt ordering is automatic)
    #pragma unroll
    for (int it = 0; it < 4; ++it) {
        const int e4 = it * 64 + lane;
        const int e = e4 * 4;
        f32x4 v;
        v.x = wtile[e + 0]; v.y = wtile[e + 1];
        v.z = wtile[e + 2]; v.w = wtile[e + 3];
        __builtin_nontemporal_store(v, (f32x4*)owave + e4);
    }
    if (lane < WF4 - 256) {
        const int e4 = 256 + lane;
        const int e = e4 * 4;
        f32x4 v;
        v.x = wtile[e + 0]; v.y = wtile[e + 1];
        v.z = wtile[e + 2]; v.w = wtile[e + 3];
        __builtin_nontemporal_store(v, (f32x4*)owave + e4);
    }
}

extern "C" void kernel_launch(void* const* d_in, const int* in_sizes, int n_in,
                              void* d_out, int out_size, void* d_ws, size_t ws_size,
                              hipStream_t stream) {
    const float* points = (const float*)d_in[0];
    const float* feats  = (const float*)d_in[1];
    const float* boxes  = (const float*)d_in[2];
    float* out_feat = (float*)d_out;
    float* out_flag = (float*)d_out + (size_t)BB * MM * SS * OUT_ROW;

    int* ws_idx = (int*)d_ws;                       // 512*512 ints = 1 MB
    int* ws_cnt = ws_idx + (size_t)BB * MM * SS;    // 512 ints

    k1_select<<<BB * MM, 512, 0, stream>>>(points, boxes, ws_idx, ws_cnt, out_flag);
    k2_gather<<<BB * MM * G2, 256, 0, stream>>>(points, feats, ws_idx, ws_cnt, out_feat);
}